// Round 4
// baseline (633.422 us; speedup 1.0000x reference)
//
#include <hip/hip_runtime.h>
#include <math.h>

// SSIM loss, fused. Inputs: pred, target fp32 (64,1,512,512). Output: scalar fp32.
//
// S = u(X)+u(Y), D = u(X)-u(Y);  4 blurred channels:
//   muS=blur(S), muD=blur(D), PS=blur(S^2), PD=blur(D^2)
//   ssim = [(muS^2-muD^2+2C1)/(muS^2+muD^2+2C1)] * [(PS-muS^2-PD+muD^2+2C2)/(PS-muS^2+PD-muD^2+2C2)]
//
// R3: packed fp32 (v_pk_fma_f32) — channels paired as float2.
// R4: occupancy push. Band 64->32 rows (grid 16x64 = 1024 blocks = 4/CU),
// chunk RY 8->4 (LDS 66->33 KB = 4 blocks/CU), horizontal = 2 waves/row.
// launch_bounds(512,8) to allow full residency (VGPR<=64, was 60).

typedef float v2f __attribute__((ext_vector_type(2)));

#define WIN 11
#define IMG 512
#define OUTW 502            // 512 - 11 + 1
#define BAND 32             // output rows per block
#define RY 4                // output rows per chunk
#define COLS2 516           // float2 columns per row (512 + 4 pad; reads reach col 515)

constexpr float A_SC  = 8.0f / 37.0f;           // std / (max-min)
constexpr float TWO_B = 2.0f * (15.5f / 37.0f); // 2*(mean-min)/(max-min)
constexpr float TWO_C1 = 2.0f * 1e-4f;
constexpr float TWO_C2 = 2.0f * 9e-4f;

__global__ __launch_bounds__(512, 8)
void ssim_main(const float* __restrict__ X, const float* __restrict__ Y,
               float* __restrict__ ws)
{
    // 2 pair-channels * 4 rows * 516 cols * 8B = 33,024 B -> 4 blocks/CU
    __shared__ __align__(16) v2f sP[2][RY][COLS2];
    __shared__ float sW[WIN];
    __shared__ float sRed[8];

    const int tid  = threadIdx.x;
    const int band = blockIdx.x;
    const int b    = blockIdx.y;
    const int y0   = band * BAND;

    if (tid == 0) {
        double g[WIN]; double sum = 0.0;
        for (int k = 0; k < WIN; ++k) { double c = k - 5; g[k] = exp(-(c * c) / 4.5); sum += g[k]; }
        for (int k = 0; k < WIN; ++k) sW[k] = (float)(g[k] / sum);
    }
    __syncthreads();
    float w[WIN];
    #pragma unroll
    for (int k = 0; k < WIN; ++k) w[k] = sW[k];

    const float* __restrict__ Xb = X + (size_t)b * (IMG * (size_t)IMG);
    const float* __restrict__ Yb = Y + (size_t)b * (IMG * (size_t)IMG);

    const int x  = tid;              // column owned in vertical pass
    const int r  = tid >> 7;         // horizontal: row slot (wave pair)
    const int gi = (tid >> 6) & 1;   // horizontal: column-group slot
    const int s  = tid & 63;
    const int x0 = 4 * (s + 64 * gi);

    float acc = 0.0f;

    // Rolling prep ring: psd[i] = {s,d} of row (ybase + i), i=0..9.
    v2f psd[10];
    #pragma unroll
    for (int i = 0; i < 10; ++i) {
        const uint32_t idx = (uint32_t)(y0 + i) * IMG + (uint32_t)x;
        const float xv = Xb[idx], yv = Yb[idx];
        v2f t; t.x = fmaf(xv + yv, A_SC, TWO_B); t.y = (xv - yv) * A_SC;
        psd[i] = t;
    }

    #pragma unroll 1
    for (int c = 0; c < BAND / RY; ++c) {
        const int ybase = y0 + c * RY;
        if (ybase < OUTW) {   // block-uniform
            v2f vsd[RY], vq[RY];
            #pragma unroll
            for (int rr = 0; rr < RY; ++rr) { vsd[rr] = (v2f)0.0f; vq[rr] = (v2f)0.0f; }

            // kept rows j = 0..9 (from ring); recompute squares (1 pk_mul)
            #pragma unroll
            for (int j = 0; j < 10; ++j) {
                const v2f a = psd[j];
                const v2f q = a * a;
                #pragma unroll
                for (int rr = 0; rr < RY; ++rr) {
                    const int k = j - rr;
                    if (k >= 0 && k < WIN) {
                        const float wk = w[k];
                        vsd[rr] += wk * a;   // -> v_pk_fma_f32
                        vq[rr]  += wk * q;
                    }
                }
            }
            // fresh rows j = 10..13: load once, scatter, park in new[]
            v2f nw[RY];
            #pragma unroll
            for (int jj = 0; jj < RY; ++jj) {
                const int j = 10 + jj;
                int yi = ybase + j; yi = yi < IMG - 1 ? yi : IMG - 1; // clamp feeds only masked rows
                const uint32_t idx = (uint32_t)yi * IMG + (uint32_t)x;
                const float xv = Xb[idx], yv = Yb[idx];
                v2f a; a.x = fmaf(xv + yv, A_SC, TWO_B); a.y = (xv - yv) * A_SC;
                const v2f q = a * a;
                #pragma unroll
                for (int rr = 0; rr < RY; ++rr) {
                    const int k = j - rr;
                    if (k >= 0 && k < WIN) {
                        const float wk = w[k];
                        vsd[rr] += wk * a;
                        vq[rr]  += wk * q;
                    }
                }
                nw[jj] = a;
            }
            // rotate ring by RY: slots 0..5 <- old 4..9; slots 6..9 <- new rows
            #pragma unroll
            for (int i = 0; i < 10 - RY; ++i) psd[i] = psd[i + RY];
            #pragma unroll
            for (int i = 0; i < RY; ++i) psd[10 - RY + i] = nw[i];

            __syncthreads();   // previous chunk's readers done
            #pragma unroll
            for (int rr = 0; rr < RY; ++rr) {
                sP[0][rr][x] = vsd[rr];  // ds_write_b64, conflict-free
                sP[1][rr][x] = vq[rr];
            }
            __syncthreads();

            // horizontal: wave 2r+gi -> row r, 64x4-wide group gi
            const int yo = ybase + r;
            if (yo < OUTW && x0 < OUTW) {
                v2f Hsd[4], Hq[4];
                #pragma unroll
                for (int p = 0; p < 2; ++p) {
                    // 16 pair-columns via 8 x b128 (x0 even -> 16B aligned)
                    const float4* q4 = (const float4*)&sP[p][r][x0];
                    v2f win2[16];
                    #pragma unroll
                    for (int j = 0; j < 8; ++j) {
                        const float4 qq = q4[j];
                        v2f lo; lo.x = qq.x; lo.y = qq.y;
                        v2f hi; hi.x = qq.z; hi.y = qq.w;
                        win2[2 * j] = lo; win2[2 * j + 1] = hi;
                    }
                    #pragma unroll
                    for (int i = 0; i < 4; ++i) {
                        v2f a = (v2f)0.0f;
                        #pragma unroll
                        for (int k = 0; k < WIN; ++k) a += w[k] * win2[i + k];
                        if (p == 0) Hsd[i] = a; else Hq[i] = a;
                    }
                }
                #pragma unroll
                for (int i = 0; i < 4; ++i) {
                    if (x0 + i < OUTW) {
                        const v2f m2 = Hsd[i] * Hsd[i];   // {mS2, mD2}
                        const v2f sg = Hq[i] - m2;        // {sS, sD}
                        const float na = m2.x - m2.y + TWO_C1;
                        const float da = m2.x + m2.y + TWO_C1;
                        const float nb = sg.x - sg.y + TWO_C2;
                        const float db = sg.x + sg.y + TWO_C2;
                        acc = fmaf(na * nb, __builtin_amdgcn_rcpf(da * db), acc);
                    }
                }
            }
        }
    }

    // block reduction -> one atomic per image
    #pragma unroll
    for (int off = 32; off > 0; off >>= 1) acc += __shfl_down(acc, off, 64);
    if ((tid & 63) == 0) sRed[tid >> 6] = acc;
    __syncthreads();
    if (tid == 0) {
        float t = 0.f;
        #pragma unroll
        for (int i = 0; i < 8; ++i) t += sRed[i];
        atomicAdd(&ws[b], t);
    }
}

__global__ void ssim_finalize(const float* __restrict__ ws, float* __restrict__ out)
{
    const int t = threadIdx.x; // one wave
    float v = ws[t] * (1.0f / (502.0f * 502.0f));
    v = v > 0.f ? v : 0.f;     // relu(per-image mean)
    #pragma unroll
    for (int off = 32; off > 0; off >>= 1) v += __shfl_down(v, off, 64);
    if (t == 0) out[0] = v * (1.0f / 64.0f);
}

extern "C" void kernel_launch(void* const* d_in, const int* in_sizes, int n_in,
                              void* d_out, int out_size, void* d_ws, size_t ws_size,
                              hipStream_t stream)
{
    const float* pred   = (const float*)d_in[0];
    const float* target = (const float*)d_in[1];
    float* out = (float*)d_out;
    float* ws  = (float*)d_ws;

    hipMemsetAsync(ws, 0, 64 * sizeof(float), stream);  // ws poisoned 0xAA each call
    ssim_main<<<dim3(16, 64), 512, 0, stream>>>(pred, target, ws);
    ssim_finalize<<<1, 64, 0, stream>>>(ws, out);
}

// Round 5
// 181.221 us; speedup vs baseline: 3.4953x; 3.4953x over previous
//
#include <hip/hip_runtime.h>
#include <math.h>

// SSIM loss, fused. Inputs: pred, target fp32 (64,1,512,512). Output: scalar fp32.
//
// S = u(X)+u(Y), D = u(X)-u(Y);  4 blurred channels:
//   muS=blur(S), muD=blur(D), PS=blur(S^2), PD=blur(D^2)
//   ssim = [(muS^2-muD^2+2C1)/(muS^2+muD^2+2C1)] * [(PS-muS^2-PD+muD^2+2C2)/(PS-muS^2+PD-muD^2+2C2)]
//
// R3: packed fp32 (v_pk_fma_f32) — channels paired as float2.
// R4: BAND 32 / RY 4 / 1024 blocks — REGRESSED: launch_bounds(512,8) forced
//     VGPR<=64, allocator spilled to scratch (WRITE_SIZE 830 MB, 8.6x slower).
// R5: same structure, launch_bounds(512,6) (VGPR cap 84) + Gaussian weights
//     held in SGPRs via readfirstlane (wave-uniform; frees 11 VGPRs).

typedef float v2f __attribute__((ext_vector_type(2)));

#define WIN 11
#define IMG 512
#define OUTW 502            // 512 - 11 + 1
#define BAND 32             // output rows per block
#define RY 4                // output rows per chunk
#define COLS2 516           // float2 columns per row (512 + 4 pad; reads reach col 515)

constexpr float A_SC  = 8.0f / 37.0f;           // std / (max-min)
constexpr float TWO_B = 2.0f * (15.5f / 37.0f); // 2*(mean-min)/(max-min)
constexpr float TWO_C1 = 2.0f * 1e-4f;
constexpr float TWO_C2 = 2.0f * 9e-4f;

__global__ __launch_bounds__(512, 6)
void ssim_main(const float* __restrict__ X, const float* __restrict__ Y,
               float* __restrict__ ws)
{
    // 2 pair-channels * 4 rows * 516 cols * 8B = 33,024 B -> 4 blocks/CU by LDS
    __shared__ __align__(16) v2f sP[2][RY][COLS2];
    __shared__ float sW[WIN];
    __shared__ float sRed[8];

    const int tid  = threadIdx.x;
    const int band = blockIdx.x;
    const int b    = blockIdx.y;
    const int y0   = band * BAND;

    if (tid == 0) {
        double g[WIN]; double sum = 0.0;
        for (int k = 0; k < WIN; ++k) { double c = k - 5; g[k] = exp(-(c * c) / 4.5); sum += g[k]; }
        for (int k = 0; k < WIN; ++k) sW[k] = (float)(g[k] / sum);
    }
    __syncthreads();
    // Wave-uniform weights -> force into SGPRs (v_pk_fma_f32 may read 1 SGPR)
    float w[WIN];
    #pragma unroll
    for (int k = 0; k < WIN; ++k)
        w[k] = __uint_as_float(__builtin_amdgcn_readfirstlane(__float_as_uint(sW[k])));

    const float* __restrict__ Xb = X + (size_t)b * (IMG * (size_t)IMG);
    const float* __restrict__ Yb = Y + (size_t)b * (IMG * (size_t)IMG);

    const int x  = tid;              // column owned in vertical pass
    const int r  = tid >> 7;         // horizontal: row slot
    const int gi = (tid >> 6) & 1;   // horizontal: column-group slot
    const int s  = tid & 63;
    const int x0 = 4 * (s + 64 * gi);

    float acc = 0.0f;

    // Rolling prep ring: psd[i] = {s,d} of row (ybase + i), i=0..9.
    v2f psd[10];
    #pragma unroll
    for (int i = 0; i < 10; ++i) {
        const uint32_t idx = (uint32_t)(y0 + i) * IMG + (uint32_t)x;
        const float xv = Xb[idx], yv = Yb[idx];
        v2f t; t.x = fmaf(xv + yv, A_SC, TWO_B); t.y = (xv - yv) * A_SC;
        psd[i] = t;
    }

    #pragma unroll 1
    for (int c = 0; c < BAND / RY; ++c) {
        const int ybase = y0 + c * RY;
        if (ybase < OUTW) {   // block-uniform
            v2f vsd[RY], vq[RY];
            #pragma unroll
            for (int rr = 0; rr < RY; ++rr) { vsd[rr] = (v2f)0.0f; vq[rr] = (v2f)0.0f; }

            // kept rows j = 0..9 (from ring); recompute squares (1 pk_mul)
            #pragma unroll
            for (int j = 0; j < 10; ++j) {
                const v2f a = psd[j];
                const v2f q = a * a;
                #pragma unroll
                for (int rr = 0; rr < RY; ++rr) {
                    const int k = j - rr;
                    if (k >= 0 && k < WIN) {
                        const float wk = w[k];
                        vsd[rr] += wk * a;   // -> v_pk_fma_f32
                        vq[rr]  += wk * q;
                    }
                }
            }
            // fresh rows j = 10..13: load once, scatter, park in nw[]
            v2f nw[RY];
            #pragma unroll
            for (int jj = 0; jj < RY; ++jj) {
                const int j = 10 + jj;
                int yi = ybase + j; yi = yi < IMG - 1 ? yi : IMG - 1; // clamp feeds only masked rows
                const uint32_t idx = (uint32_t)yi * IMG + (uint32_t)x;
                const float xv = Xb[idx], yv = Yb[idx];
                v2f a; a.x = fmaf(xv + yv, A_SC, TWO_B); a.y = (xv - yv) * A_SC;
                const v2f q = a * a;
                #pragma unroll
                for (int rr = 0; rr < RY; ++rr) {
                    const int k = j - rr;
                    if (k >= 0 && k < WIN) {
                        const float wk = w[k];
                        vsd[rr] += wk * a;
                        vq[rr]  += wk * q;
                    }
                }
                nw[jj] = a;
            }
            // rotate ring by RY
            #pragma unroll
            for (int i = 0; i < 10 - RY; ++i) psd[i] = psd[i + RY];
            #pragma unroll
            for (int i = 0; i < RY; ++i) psd[10 - RY + i] = nw[i];

            __syncthreads();   // previous chunk's readers done
            #pragma unroll
            for (int rr = 0; rr < RY; ++rr) {
                sP[0][rr][x] = vsd[rr];  // ds_write_b64, conflict-free
                sP[1][rr][x] = vq[rr];
            }
            __syncthreads();

            // horizontal: wave 2r+gi -> row r, 64x4-wide group gi
            const int yo = ybase + r;
            if (yo < OUTW && x0 < OUTW) {
                v2f Hsd[4], Hq[4];
                #pragma unroll
                for (int p = 0; p < 2; ++p) {
                    const float4* q4 = (const float4*)&sP[p][r][x0];
                    v2f win2[16];
                    #pragma unroll
                    for (int j = 0; j < 8; ++j) {
                        const float4 qq = q4[j];
                        v2f lo; lo.x = qq.x; lo.y = qq.y;
                        v2f hi; hi.x = qq.z; hi.y = qq.w;
                        win2[2 * j] = lo; win2[2 * j + 1] = hi;
                    }
                    #pragma unroll
                    for (int i = 0; i < 4; ++i) {
                        v2f a = (v2f)0.0f;
                        #pragma unroll
                        for (int k = 0; k < WIN; ++k) a += w[k] * win2[i + k];
                        if (p == 0) Hsd[i] = a; else Hq[i] = a;
                    }
                }
                #pragma unroll
                for (int i = 0; i < 4; ++i) {
                    if (x0 + i < OUTW) {
                        const v2f m2 = Hsd[i] * Hsd[i];   // {mS2, mD2}
                        const v2f sg = Hq[i] - m2;        // {sS, sD}
                        const float na = m2.x - m2.y + TWO_C1;
                        const float da = m2.x + m2.y + TWO_C1;
                        const float nb = sg.x - sg.y + TWO_C2;
                        const float db = sg.x + sg.y + TWO_C2;
                        acc = fmaf(na * nb, __builtin_amdgcn_rcpf(da * db), acc);
                    }
                }
            }
        }
    }

    // block reduction -> one atomic per image
    #pragma unroll
    for (int off = 32; off > 0; off >>= 1) acc += __shfl_down(acc, off, 64);
    if ((tid & 63) == 0) sRed[tid >> 6] = acc;
    __syncthreads();
    if (tid == 0) {
        float t = 0.f;
        #pragma unroll
        for (int i = 0; i < 8; ++i) t += sRed[i];
        atomicAdd(&ws[b], t);
    }
}

__global__ void ssim_finalize(const float* __restrict__ ws, float* __restrict__ out)
{
    const int t = threadIdx.x; // one wave
    float v = ws[t] * (1.0f / (502.0f * 502.0f));
    v = v > 0.f ? v : 0.f;     // relu(per-image mean)
    #pragma unroll
    for (int off = 32; off > 0; off >>= 1) v += __shfl_down(v, off, 64);
    if (t == 0) out[0] = v * (1.0f / 64.0f);
}

extern "C" void kernel_launch(void* const* d_in, const int* in_sizes, int n_in,
                              void* d_out, int out_size, void* d_ws, size_t ws_size,
                              hipStream_t stream)
{
    const float* pred   = (const float*)d_in[0];
    const float* target = (const float*)d_in[1];
    float* out = (float*)d_out;
    float* ws  = (float*)d_ws;

    hipMemsetAsync(ws, 0, 64 * sizeof(float), stream);  // ws poisoned 0xAA each call
    ssim_main<<<dim3(16, 64), 512, 0, stream>>>(pred, target, ws);
    ssim_finalize<<<1, 64, 0, stream>>>(ws, out);
}

// Round 6
// 165.131 us; speedup vs baseline: 3.8359x; 1.0974x over previous
//
#include <hip/hip_runtime.h>
#include <math.h>

// SSIM loss, fused. Inputs: pred, target fp32 (64,1,512,512). Output: scalar fp32.
//
// S = u(X)+u(Y), D = u(X)-u(Y);  4 blurred channels:
//   muS=blur(S), muD=blur(D), PS=blur(S^2), PD=blur(D^2)
//   ssim = [(muS^2-muD^2+2C1)/(muS^2+muD^2+2C1)] * [(PS-muS^2-PD+muD^2+2C2)/(PS-muS^2+PD-muD^2+2C2)]
//
// R3: packed fp32 (v_pk_fma_f32), float2 channel pairs.          63 us, VGPR 60
// R4: launch_bounds(512,8) -> allocator spilled (VGPR 32, 830MB) 545 us
// R5: launch_bounds(512,6) -> STILL spills (VGPR 40, 33MB)        85 us
//   => min-waves >= 6 makes the allocator overshoot below its cap. Never again.
// R6: launch_bounds(512,4) (proven clean) + EARN occupancy: horizontal pass
//     restructured as streaming conv (4 live accumulators, 7 b128 reads) so
//     natural VGPR demand <= 64 -> HW can run 8 waves/SIMD with 33KB LDS.

typedef float v2f __attribute__((ext_vector_type(2)));

#define WIN 11
#define IMG 512
#define OUTW 502            // 512 - 11 + 1
#define BAND 32             // output rows per block
#define RY 4                // output rows per chunk
#define COLS2 516           // float2 columns per row (512 + 4 pad)

constexpr float A_SC  = 8.0f / 37.0f;           // std / (max-min)
constexpr float TWO_B = 2.0f * (15.5f / 37.0f); // 2*(mean-min)/(max-min)
constexpr float TWO_C1 = 2.0f * 1e-4f;
constexpr float TWO_C2 = 2.0f * 9e-4f;

__global__ __launch_bounds__(512, 4)
void ssim_main(const float* __restrict__ X, const float* __restrict__ Y,
               float* __restrict__ ws)
{
    // 2 pair-channels * 4 rows * 516 cols * 8B = 33,024 B -> 4 blocks/CU by LDS
    __shared__ __align__(16) v2f sP[2][RY][COLS2];
    __shared__ float sW[WIN];
    __shared__ float sRed[8];

    const int tid  = threadIdx.x;
    const int band = blockIdx.x;
    const int b    = blockIdx.y;
    const int y0   = band * BAND;

    if (tid == 0) {
        double g[WIN]; double sum = 0.0;
        for (int k = 0; k < WIN; ++k) { double c = k - 5; g[k] = exp(-(c * c) / 4.5); sum += g[k]; }
        for (int k = 0; k < WIN; ++k) sW[k] = (float)(g[k] / sum);
    }
    __syncthreads();
    // Wave-uniform weights -> SGPRs (v_pk_fma_f32 may read 1 SGPR operand)
    float w[WIN];
    #pragma unroll
    for (int k = 0; k < WIN; ++k)
        w[k] = __uint_as_float(__builtin_amdgcn_readfirstlane(__float_as_uint(sW[k])));

    const float* __restrict__ Xb = X + (size_t)b * (IMG * (size_t)IMG);
    const float* __restrict__ Yb = Y + (size_t)b * (IMG * (size_t)IMG);

    const int x  = tid;              // column owned in vertical pass
    const int r  = tid >> 7;         // horizontal: row slot
    const int gi = (tid >> 6) & 1;   // horizontal: column-group slot
    const int s  = tid & 63;
    const int x0 = 4 * (s + 64 * gi);

    float acc = 0.0f;

    // Rolling prep ring: psd[i] = {s,d} of row (ybase + i), i=0..9.
    v2f psd[10];
    #pragma unroll
    for (int i = 0; i < 10; ++i) {
        const uint32_t idx = (uint32_t)(y0 + i) * IMG + (uint32_t)x;
        const float xv = Xb[idx], yv = Yb[idx];
        v2f t; t.x = fmaf(xv + yv, A_SC, TWO_B); t.y = (xv - yv) * A_SC;
        psd[i] = t;
    }

    #pragma unroll 1
    for (int c = 0; c < BAND / RY; ++c) {
        const int ybase = y0 + c * RY;
        if (ybase < OUTW) {   // block-uniform
            v2f vsd[RY], vq[RY];
            #pragma unroll
            for (int rr = 0; rr < RY; ++rr) { vsd[rr] = (v2f)0.0f; vq[rr] = (v2f)0.0f; }

            // kept rows j = 0..9 (from ring); recompute squares (1 pk_mul)
            #pragma unroll
            for (int j = 0; j < 10; ++j) {
                const v2f a = psd[j];
                const v2f q = a * a;
                #pragma unroll
                for (int rr = 0; rr < RY; ++rr) {
                    const int k = j - rr;
                    if (k >= 0 && k < WIN) {
                        const float wk = w[k];
                        vsd[rr] += wk * a;   // -> v_pk_fma_f32
                        vq[rr]  += wk * q;
                    }
                }
            }
            // fresh rows j = 10..13: load once, scatter, park in nw[]
            v2f nw[RY];
            #pragma unroll
            for (int jj = 0; jj < RY; ++jj) {
                const int j = 10 + jj;
                int yi = ybase + j; yi = yi < IMG - 1 ? yi : IMG - 1; // clamp feeds only masked rows
                const uint32_t idx = (uint32_t)yi * IMG + (uint32_t)x;
                const float xv = Xb[idx], yv = Yb[idx];
                v2f a; a.x = fmaf(xv + yv, A_SC, TWO_B); a.y = (xv - yv) * A_SC;
                const v2f q = a * a;
                #pragma unroll
                for (int rr = 0; rr < RY; ++rr) {
                    const int k = j - rr;
                    if (k >= 0 && k < WIN) {
                        const float wk = w[k];
                        vsd[rr] += wk * a;
                        vq[rr]  += wk * q;
                    }
                }
                nw[jj] = a;
            }
            // rotate ring by RY
            #pragma unroll
            for (int i = 0; i < 10 - RY; ++i) psd[i] = psd[i + RY];
            #pragma unroll
            for (int i = 0; i < RY; ++i) psd[10 - RY + i] = nw[i];

            __syncthreads();   // previous chunk's readers done
            #pragma unroll
            for (int rr = 0; rr < RY; ++rr) {
                sP[0][rr][x] = vsd[rr];  // ds_write_b64, conflict-free
                sP[1][rr][x] = vq[rr];
            }
            __syncthreads();

            // horizontal: wave 2r+gi -> row r, 64x4-wide group gi.
            // Streaming conv: 7 b128 reads (14 pair-columns), 4 live accumulators.
            // Column j feeds output i for i in [j-10, j] n [0,3], weight w[j-i].
            const int yo = ybase + r;
            if (yo < OUTW && x0 < OUTW) {
                v2f Hsd[4], Hq[4];
                #pragma unroll
                for (int p = 0; p < 2; ++p) {
                    v2f a0 = (v2f)0.0f, a1 = (v2f)0.0f, a2 = (v2f)0.0f, a3 = (v2f)0.0f;
                    const float4* q4 = (const float4*)&sP[p][r][x0];
                    #pragma unroll
                    for (int j4 = 0; j4 < 7; ++j4) {
                        const float4 qq = q4[j4];
                        #pragma unroll
                        for (int h = 0; h < 2; ++h) {
                            const int j = 2 * j4 + h;
                            v2f col; col.x = h ? qq.z : qq.x; col.y = h ? qq.w : qq.y;
                            if (j - 0 >= 0 && j - 0 < WIN) a0 += w[j]     * col;
                            if (j - 1 >= 0 && j - 1 < WIN) a1 += w[j - 1] * col;
                            if (j - 2 >= 0 && j - 2 < WIN) a2 += w[j - 2] * col;
                            if (j - 3 >= 0 && j - 3 < WIN) a3 += w[j - 3] * col;
                        }
                    }
                    if (p == 0) { Hsd[0] = a0; Hsd[1] = a1; Hsd[2] = a2; Hsd[3] = a3; }
                    else        { Hq[0]  = a0; Hq[1]  = a1; Hq[2]  = a2; Hq[3]  = a3; }
                }
                #pragma unroll
                for (int i = 0; i < 4; ++i) {
                    if (x0 + i < OUTW) {
                        const v2f m2 = Hsd[i] * Hsd[i];   // {mS2, mD2}
                        const v2f sg = Hq[i] - m2;        // {sS, sD}
                        const float na = m2.x - m2.y + TWO_C1;
                        const float da = m2.x + m2.y + TWO_C1;
                        const float nb = sg.x - sg.y + TWO_C2;
                        const float db = sg.x + sg.y + TWO_C2;
                        acc = fmaf(na * nb, __builtin_amdgcn_rcpf(da * db), acc);
                    }
                }
            }
        }
    }

    // block reduction -> one atomic per image
    #pragma unroll
    for (int off = 32; off > 0; off >>= 1) acc += __shfl_down(acc, off, 64);
    if ((tid & 63) == 0) sRed[tid >> 6] = acc;
    __syncthreads();
    if (tid == 0) {
        float t = 0.f;
        #pragma unroll
        for (int i = 0; i < 8; ++i) t += sRed[i];
        atomicAdd(&ws[b], t);
    }
}

__global__ void ssim_finalize(const float* __restrict__ ws, float* __restrict__ out)
{
    const int t = threadIdx.x; // one wave
    float v = ws[t] * (1.0f / (502.0f * 502.0f));
    v = v > 0.f ? v : 0.f;     // relu(per-image mean)
    #pragma unroll
    for (int off = 32; off > 0; off >>= 1) v += __shfl_down(v, off, 64);
    if (t == 0) out[0] = v * (1.0f / 64.0f);
}

extern "C" void kernel_launch(void* const* d_in, const int* in_sizes, int n_in,
                              void* d_out, int out_size, void* d_ws, size_t ws_size,
                              hipStream_t stream)
{
    const float* pred   = (const float*)d_in[0];
    const float* target = (const float*)d_in[1];
    float* out = (float*)d_out;
    float* ws  = (float*)d_ws;

    hipMemsetAsync(ws, 0, 64 * sizeof(float), stream);  // ws poisoned 0xAA each call
    ssim_main<<<dim3(16, 64), 512, 0, stream>>>(pred, target, ws);
    ssim_finalize<<<1, 64, 0, stream>>>(ws, out);
}

// Round 7
// 159.159 us; speedup vs baseline: 3.9798x; 1.0375x over previous
//
#include <hip/hip_runtime.h>
#include <math.h>

// SSIM loss, fused. Inputs: pred, target fp32 (64,1,512,512). Output: scalar fp32.
//
// S = u(X)+u(Y), D = u(X)-u(Y);  4 blurred channels:
//   muS=blur(S), muD=blur(D), PS=blur(S^2), PD=blur(D^2)
//   ssim = [(muS^2-muD^2+2C1)/(muS^2+muD^2+2C1)] * [(PS-muS^2-PD+muD^2+2C2)/(PS-muS^2+PD-muD^2+2C2)]
//
// R3: pk_fma float2 pairs, BAND 64/RY 8, 2 barriers/chunk.        63 us, VGPR 60
// R4/R5: launch_bounds min-waves>=6 => allocator spills. Never again.
// R6: BAND 32/RY 4, more blocks/CU -> occupancy DIDN'T rise (37%), 72.5 us.
//   => stalls are correlated barrier waits; co-resident blocks don't fix them.
// R7: single-barrier ping-pong pipeline. BAND 64, RY 4, two LDS buffers
//     (66 KB, 2 blocks/CU like R3). Per iter: global loads(c+1) issued first,
//     horizontal(c) reads buf[c&1], vertical(c+1) writes buf[(c+1)&1], ONE
//     __syncthreads. Loads hide under horizontal FMAs; write->read barrier gone.

typedef float v2f __attribute__((ext_vector_type(2)));

#define WIN 11
#define IMG 512
#define OUTW 502            // 512 - 11 + 1
#define BAND 64             // output rows per block
#define RY 4                // output rows per chunk
#define NCHUNK (BAND / RY)  // 16
#define COLS2 516           // float2 columns per row (512 + 4 pad)

constexpr float A_SC  = 8.0f / 37.0f;           // std / (max-min)
constexpr float TWO_B = 2.0f * (15.5f / 37.0f); // 2*(mean-min)/(max-min)
constexpr float TWO_C1 = 2.0f * 1e-4f;
constexpr float TWO_C2 = 2.0f * 9e-4f;

__global__ __launch_bounds__(512, 4)
void ssim_main(const float* __restrict__ X, const float* __restrict__ Y,
               float* __restrict__ ws)
{
    // 2 bufs * 2 pair-channels * 4 rows * 516 cols * 8B = 66,048 B -> 2 blocks/CU
    __shared__ __align__(16) v2f sP[2][2][RY][COLS2];
    __shared__ float sW[WIN];
    __shared__ float sRed[8];

    const int tid  = threadIdx.x;
    const int band = blockIdx.x;
    const int b    = blockIdx.y;
    const int y0   = band * BAND;

    if (tid == 0) {
        double g[WIN]; double sum = 0.0;
        for (int k = 0; k < WIN; ++k) { double c = k - 5; g[k] = exp(-(c * c) / 4.5); sum += g[k]; }
        for (int k = 0; k < WIN; ++k) sW[k] = (float)(g[k] / sum);
    }
    __syncthreads();
    // Wave-uniform weights -> SGPRs (v_pk_fma_f32 may read 1 SGPR operand)
    float w[WIN];
    #pragma unroll
    for (int k = 0; k < WIN; ++k)
        w[k] = __uint_as_float(__builtin_amdgcn_readfirstlane(__float_as_uint(sW[k])));

    const float* __restrict__ Xb = X + (size_t)b * (IMG * (size_t)IMG);
    const float* __restrict__ Yb = Y + (size_t)b * (IMG * (size_t)IMG);

    const int x  = tid;              // column owned in vertical pass
    const int r  = tid >> 7;         // horizontal: row slot (0..3)
    const int gi = (tid >> 6) & 1;   // horizontal: column-group slot
    const int s  = tid & 63;
    const int x0 = 4 * (s + 64 * gi);

    float acc = 0.0f;

    // Rolling prep ring: psd[i] = {s,d} of row (nbase + i), i=0..9, where
    // nbase is the base row of the NEXT chunk to be vertical-blurred.
    v2f psd[10];
    #pragma unroll
    for (int i = 0; i < 10; ++i) {
        const uint32_t idx = (uint32_t)(y0 + i) * IMG + (uint32_t)x;
        const float xv = Xb[idx], yv = Yb[idx];
        v2f t; t.x = fmaf(xv + yv, A_SC, TWO_B); t.y = (xv - yv) * A_SC;
        psd[i] = t;
    }

    // c = -1: prologue (vertical chunk 0 only). c = 0..15: horizontal c (+ vertical c+1).
    #pragma unroll 1
    for (int c = -1; c < NCHUNK; ++c) {
        const int vchunk = c + 1;               // chunk to vertical-blur this iter
        const bool dovert = (vchunk < NCHUNK);
        const int nbase = y0 + vchunk * RY;

        // ---- (a) issue fresh-row global loads for chunk c+1 early
        float fx[RY], fy[RY];
        if (dovert) {
            #pragma unroll
            for (int jj = 0; jj < RY; ++jj) {
                int yi = nbase + 10 + jj; yi = yi < IMG - 1 ? yi : IMG - 1; // clamp feeds masked rows only
                const uint32_t idx = (uint32_t)yi * IMG + (uint32_t)x;
                fx[jj] = Xb[idx]; fy[jj] = Yb[idx];
            }
        }

        // ---- (b) horizontal chunk c from buf[c&1] (written last iteration)
        if (c >= 0) {
            const int ybase = y0 + c * RY;
            const int yo = ybase + r;
            if (yo < OUTW && x0 < OUTW) {
                const int bufc = c & 1;
                v2f Hsd[4], Hq[4];
                #pragma unroll
                for (int p = 0; p < 2; ++p) {
                    v2f a0 = (v2f)0.0f, a1 = (v2f)0.0f, a2 = (v2f)0.0f, a3 = (v2f)0.0f;
                    const float4* q4 = (const float4*)&sP[bufc][p][r][x0];
                    #pragma unroll
                    for (int j4 = 0; j4 < 7; ++j4) {
                        const float4 qq = q4[j4];
                        #pragma unroll
                        for (int h = 0; h < 2; ++h) {
                            const int j = 2 * j4 + h;
                            v2f col; col.x = h ? qq.z : qq.x; col.y = h ? qq.w : qq.y;
                            if (j - 0 >= 0 && j - 0 < WIN) a0 += w[j]     * col;
                            if (j - 1 >= 0 && j - 1 < WIN) a1 += w[j - 1] * col;
                            if (j - 2 >= 0 && j - 2 < WIN) a2 += w[j - 2] * col;
                            if (j - 3 >= 0 && j - 3 < WIN) a3 += w[j - 3] * col;
                        }
                    }
                    if (p == 0) { Hsd[0] = a0; Hsd[1] = a1; Hsd[2] = a2; Hsd[3] = a3; }
                    else        { Hq[0]  = a0; Hq[1]  = a1; Hq[2]  = a2; Hq[3]  = a3; }
                }
                #pragma unroll
                for (int i = 0; i < 4; ++i) {
                    if (x0 + i < OUTW) {
                        const v2f m2 = Hsd[i] * Hsd[i];   // {mS2, mD2}
                        const v2f sg = Hq[i] - m2;        // {sS, sD}
                        const float na = m2.x - m2.y + TWO_C1;
                        const float da = m2.x + m2.y + TWO_C1;
                        const float nb = sg.x - sg.y + TWO_C2;
                        const float db = sg.x + sg.y + TWO_C2;
                        acc = fmaf(na * nb, __builtin_amdgcn_rcpf(da * db), acc);
                    }
                }
            }
        }

        // ---- (c) vertical chunk c+1 -> buf[(c+1)&1]
        if (dovert) {
            const int bufn = vchunk & 1;
            v2f vsd[RY], vq[RY];
            #pragma unroll
            for (int rr = 0; rr < RY; ++rr) { vsd[rr] = (v2f)0.0f; vq[rr] = (v2f)0.0f; }

            // kept rows j = 0..9 (from ring, rows nbase..nbase+9)
            #pragma unroll
            for (int j = 0; j < 10; ++j) {
                const v2f a = psd[j];
                const v2f q = a * a;
                #pragma unroll
                for (int rr = 0; rr < RY; ++rr) {
                    const int k = j - rr;
                    if (k >= 0 && k < WIN) {
                        const float wk = w[k];
                        vsd[rr] += wk * a;   // -> v_pk_fma_f32
                        vq[rr]  += wk * q;
                    }
                }
            }
            // fresh rows j = 10..13 from the early loads
            v2f nw[RY];
            #pragma unroll
            for (int jj = 0; jj < RY; ++jj) {
                const int j = 10 + jj;
                v2f a; a.x = fmaf(fx[jj] + fy[jj], A_SC, TWO_B); a.y = (fx[jj] - fy[jj]) * A_SC;
                const v2f q = a * a;
                #pragma unroll
                for (int rr = 0; rr < RY; ++rr) {
                    const int k = j - rr;
                    if (k >= 0 && k < WIN) {
                        const float wk = w[k];
                        vsd[rr] += wk * a;
                        vq[rr]  += wk * q;
                    }
                }
                nw[jj] = a;
            }
            // rotate ring by RY
            #pragma unroll
            for (int i = 0; i < 10 - RY; ++i) psd[i] = psd[i + RY];
            #pragma unroll
            for (int i = 0; i < RY; ++i) psd[10 - RY + i] = nw[i];

            #pragma unroll
            for (int rr = 0; rr < RY; ++rr) {
                sP[bufn][0][rr][x] = vsd[rr];  // ds_write_b64, conflict-free
                sP[bufn][1][rr][x] = vq[rr];
            }
        }

        __syncthreads();   // single barrier: writes(c+1) visible, readers(c) done
    }

    // block reduction -> one atomic per image
    #pragma unroll
    for (int off = 32; off > 0; off >>= 1) acc += __shfl_down(acc, off, 64);
    if ((tid & 63) == 0) sRed[tid >> 6] = acc;
    __syncthreads();
    if (tid == 0) {
        float t = 0.f;
        #pragma unroll
        for (int i = 0; i < 8; ++i) t += sRed[i];
        atomicAdd(&ws[b], t);
    }
}

__global__ void ssim_finalize(const float* __restrict__ ws, float* __restrict__ out)
{
    const int t = threadIdx.x; // one wave
    float v = ws[t] * (1.0f / (502.0f * 502.0f));
    v = v > 0.f ? v : 0.f;     // relu(per-image mean)
    #pragma unroll
    for (int off = 32; off > 0; off >>= 1) v += __shfl_down(v, off, 64);
    if (t == 0) out[0] = v * (1.0f / 64.0f);
}

extern "C" void kernel_launch(void* const* d_in, const int* in_sizes, int n_in,
                              void* d_out, int out_size, void* d_ws, size_t ws_size,
                              hipStream_t stream)
{
    const float* pred   = (const float*)d_in[0];
    const float* target = (const float*)d_in[1];
    float* out = (float*)d_out;
    float* ws  = (float*)d_ws;

    hipMemsetAsync(ws, 0, 64 * sizeof(float), stream);  // ws poisoned 0xAA each call
    ssim_main<<<dim3(8, 64), 512, 0, stream>>>(pred, target, ws);
    ssim_finalize<<<1, 64, 0, stream>>>(ws, out);
}